// Round 15
// baseline (1259.668 us; speedup 1.0000x reference)
//
#include <hip/hip_runtime.h>
#include <math.h>

// Problem constants
// B=256, T=512, E=768, Hd=50, 4*Hd=200, H=100, K=11, START=9, STOP=10, NEG=-1000
// M = B*T = 131072

typedef _Float16 half8 __attribute__((ext_vector_type(8)));
typedef _Float16 half4 __attribute__((ext_vector_type(4)));
typedef float f32x4 __attribute__((ext_vector_type(4)));

// Non-draining workgroup barrier (learn_hip m201 pattern).
#define LBAR() do {                                   \
    __builtin_amdgcn_sched_barrier(0);                \
    asm volatile("s_waitcnt lgkmcnt(0)");             \
    __builtin_amdgcn_s_barrier();                     \
    __builtin_amdgcn_sched_barrier(0);                \
} while (0)

// Single-wave LDS fence: order ds_write -> ds_read without a barrier.
#define LW() do {                                     \
    __builtin_amdgcn_sched_barrier(0);                \
    asm volatile("s_waitcnt lgkmcnt(0)");             \
    __builtin_amdgcn_sched_barrier(0);                \
} while (0)

// ---------------------------------------------------------------------------
// Kernel 0: one-time hi/lo fp16 split of concat(W_ih_f, W_ih_b) [400][768].
// ---------------------------------------------------------------------------
__global__ __launch_bounds__(256) void k_bsplit(
    const float* __restrict__ Wf,     // [200][768]
    const float* __restrict__ Wb,     // [200][768]
    _Float16* __restrict__ Bh,        // [400*768]
    _Float16* __restrict__ Bl)
{
    const int i = blockIdx.x * 256 + threadIdx.x;   // 0..307199
    if (i < 400 * 768) {
        const int n = i / 768;
        const int k = i - n * 768;
        const float v = (n < 200) ? Wf[n * 768 + k] : Wb[(n - 200) * 768 + k];
        const _Float16 hi = (_Float16)v;
        Bh[i] = hi;
        Bl[i] = (_Float16)(v - (float)hi);
    }
}

// ---------------------------------------------------------------------------
// Kernel 1: xw[M][400] = emb[M][768] @ concat(W_ih_f, W_ih_b)^T
// Split-precision fp16 MFMA; non-draining LBAR K-loop; pre-split B.
// ---------------------------------------------------------------------------
__global__ __launch_bounds__(256) void k_gemm_split(
    const float* __restrict__ emb,
    const _Float16* __restrict__ Bhg, // [400][768] pre-split hi
    const _Float16* __restrict__ Blg, // [400][768] pre-split lo
    float* __restrict__ xw)           // [M][400]
{
    __shared__ _Float16 Ah[128 * 64];
    __shared__ _Float16 Al[128 * 64];
    __shared__ _Float16 Bh[80 * 64];
    __shared__ _Float16 Bl[80 * 64];

    const int bid = blockIdx.x;
    const int wg  = (bid & 7) * 640 + (bid >> 3);
    const int mt  = wg / 5;
    const int nb  = wg - mt * 5;
    const size_t m0 = (size_t)mt * 128;
    const int n0 = nb * 80;

    const int tid  = threadIdx.x;
    const int lane = tid & 63;
    const int w    = tid >> 6;        // wave 0..3, rows w*32..+31
    const int grp  = lane >> 4;       // 0..3
    const int r16  = lane & 15;

    f32x4 acc[2][5];
    #pragma unroll
    for (int m = 0; m < 2; ++m)
        #pragma unroll
        for (int n = 0; n < 5; ++n) acc[m][n] = (f32x4){0.f, 0.f, 0.f, 0.f};

    // prefetch kt=0
    float4 apf[8];
    half4  bph[5], bpl[5];
    #pragma unroll
    for (int j = 0; j < 8; ++j) {
        const int flat = j * 256 + tid;
        const int row  = flat >> 4;
        const int q    = flat & 15;
        apf[j] = *(const float4*)(emb + (m0 + row) * 768 + q * 4);
    }
    #pragma unroll
    for (int j = 0; j < 5; ++j) {
        const int flat = j * 256 + tid;      // 0..1279
        const int row  = flat >> 4;          // 0..79
        const int q    = flat & 15;
        const size_t src = (size_t)(n0 + row) * 768 + q * 4;
        bph[j] = *(const half4*)(Bhg + src);
        bpl[j] = *(const half4*)(Blg + src);
    }

    for (int kt = 0; kt < 12; ++kt) {
        LBAR();   // all waves done reading LDS from previous iteration

        #pragma unroll
        for (int j = 0; j < 8; ++j) {
            const int flat = j * 256 + tid;
            const int row  = flat >> 4;
            const int q    = flat & 15;
            const float4 v = apf[j];
            half4 hv, lv;
            hv[0] = (_Float16)v.x; lv[0] = (_Float16)(v.x - (float)hv[0]);
            hv[1] = (_Float16)v.y; lv[1] = (_Float16)(v.y - (float)hv[1]);
            hv[2] = (_Float16)v.z; lv[2] = (_Float16)(v.z - (float)hv[2]);
            hv[3] = (_Float16)v.w; lv[3] = (_Float16)(v.w - (float)hv[3]);
            const int s    = (q >> 1) ^ (row & 7);
            const int addr = row * 64 + s * 8 + (q & 1) * 4;
            *(half4*)(Ah + addr) = hv;
            *(half4*)(Al + addr) = lv;
        }
        #pragma unroll
        for (int j = 0; j < 5; ++j) {
            const int flat = j * 256 + tid;
            const int row  = flat >> 4;
            const int q    = flat & 15;
            const int s    = (q >> 1) ^ (row & 7);
            const int addr = row * 64 + s * 8 + (q & 1) * 4;
            *(half4*)(Bh + addr) = bph[j];
            *(half4*)(Bl + addr) = bpl[j];
        }

        if (kt + 1 < 12) {
            const int k0 = (kt + 1) * 64;
            #pragma unroll
            for (int j = 0; j < 8; ++j) {
                const int flat = j * 256 + tid;
                const int row  = flat >> 4;
                const int q    = flat & 15;
                apf[j] = *(const float4*)(emb + (m0 + row) * 768 + k0 + q * 4);
            }
            #pragma unroll
            for (int j = 0; j < 5; ++j) {
                const int flat = j * 256 + tid;
                const int row  = flat >> 4;
                const int q    = flat & 15;
                const size_t src = (size_t)(n0 + row) * 768 + k0 + q * 4;
                bph[j] = *(const half4*)(Bhg + src);
                bpl[j] = *(const half4*)(Blg + src);
            }
        }

        LBAR();   // staged tile visible; prefetch stays in flight

        #pragma unroll
        for (int ks = 0; ks < 2; ++ks) {
            const int kslot = ks * 4 + grp;
            half8 ah[2], al[2], bh[5], bl[5];
            #pragma unroll
            for (int m = 0; m < 2; ++m) {
                const int row = w * 32 + m * 16 + r16;
                const int ad  = row * 64 + (kslot ^ (row & 7)) * 8;
                ah[m] = *(half8*)(Ah + ad);
                al[m] = *(half8*)(Al + ad);
            }
            #pragma unroll
            for (int n = 0; n < 5; ++n) {
                const int row = n * 16 + r16;
                const int ad  = row * 64 + (kslot ^ (row & 7)) * 8;
                bh[n] = *(half8*)(Bh + ad);
                bl[n] = *(half8*)(Bl + ad);
            }
            #pragma unroll
            for (int m = 0; m < 2; ++m)
                #pragma unroll
                for (int n = 0; n < 5; ++n) {
                    acc[m][n] = __builtin_amdgcn_mfma_f32_16x16x32_f16(ah[m], bh[n], acc[m][n], 0, 0, 0);
                    acc[m][n] = __builtin_amdgcn_mfma_f32_16x16x32_f16(ah[m], bl[n], acc[m][n], 0, 0, 0);
                    acc[m][n] = __builtin_amdgcn_mfma_f32_16x16x32_f16(al[m], bh[n], acc[m][n], 0, 0, 0);
                }
        }
    }

    #pragma unroll
    for (int m = 0; m < 2; ++m) {
        #pragma unroll
        for (int n = 0; n < 5; ++n) {
            #pragma unroll
            for (int i = 0; i < 4; ++i) {
                const size_t row = m0 + w * 32 + m * 16 + (lane >> 4) * 4 + i;
                const int    col = n0 + n * 16 + (lane & 15);
                xw[row * 400 + col] = acc[m][n][i];
            }
        }
    }
}

// ---------------------------------------------------------------------------
// Kernel 2: bidirectional LSTM — SINGLE-WAVE, ZERO-EXCHANGE structure.
// One wave (64 thr) per (batch,dir); thread u owns unit u and computes ALL
// FOUR of its gate sums itself (4x50 FMAs, weights parked in 200 AGPRs via
// the R14-proven v_accvgpr_write producer — cannot be sunk/spilled). Gate
// values are thread-local => NO g_s exchange and NO s_barrier at all; a
// single lgkmcnt fence orders the h_s write->read (single-wave lockstep).
// This removes the cross-wave producer-consumer handoff that every prior
// variant shared. Gate-sum order, loads, and nonlin are bit-identical to
// R1 (skipped zero-pads are bitwise no-ops).
// ---------------------------------------------------------------------------
__global__ __launch_bounds__(64, 1) void k_lstm(
    const float* __restrict__ xw,     // [131072][400] (fwd gates 0..199, bwd 200..399)
    const float* __restrict__ Whh_f,  // [200][50]
    const float* __restrict__ Whh_b,
    const float* __restrict__ bf_,    // [200]
    const float* __restrict__ bb_,
    float* __restrict__ hout)         // [131072][100] (fwd 0..49, bwd 50..99)
{
    const int b    = blockIdx.x >> 1;
    const int dir  = blockIdx.x & 1;
    const int lane = threadIdx.x;
    const bool act = (lane < 50);
    const int u    = act ? lane : 49;

    __shared__ __align__(16) float h_s[52];

    const float* Whh  = dir ? Whh_b : Whh_f;
    const float* bias = dir ? bb_ : bf_;

    // load 4 gate rows for unit u
    float wt0[50], wt1[50], wt2[50], wt3[50];
    #pragma unroll
    for (int j = 0; j < 50; ++j) {
        wt0[j] = Whh[(0 * 50 + u) * 50 + j];
        wt1[j] = Whh[(1 * 50 + u) * 50 + j];
        wt2[j] = Whh[(2 * 50 + u) * 50 + j];
        wt3[j] = Whh[(3 * 50 + u) * 50 + j];
    }
    const float bg0 = bias[u];
    const float bg1 = bias[50 + u];
    const float bg2 = bias[100 + u];
    const float bg3 = bias[150 + u];

    // park all 200 weights in AGPRs (producer asm: not sinkable/spillable)
    #define PARK(g, j) float W##g##_##j; \
        asm volatile("v_accvgpr_write_b32 %0, %1" : "=a"(W##g##_##j) : "v"(wt##g[j]))
    #define REP50(M, g) \
        M(g,0);  M(g,1);  M(g,2);  M(g,3);  M(g,4);  M(g,5);  M(g,6);  M(g,7);  M(g,8);  M(g,9);  \
        M(g,10); M(g,11); M(g,12); M(g,13); M(g,14); M(g,15); M(g,16); M(g,17); M(g,18); M(g,19); \
        M(g,20); M(g,21); M(g,22); M(g,23); M(g,24); M(g,25); M(g,26); M(g,27); M(g,28); M(g,29); \
        M(g,30); M(g,31); M(g,32); M(g,33); M(g,34); M(g,35); M(g,36); M(g,37); M(g,38); M(g,39); \
        M(g,40); M(g,41); M(g,42); M(g,43); M(g,44); M(g,45); M(g,46); M(g,47); M(g,48); M(g,49)
    REP50(PARK, 0);
    REP50(PARK, 1);
    REP50(PARK, 2);
    REP50(PARK, 3);
    #undef PARK

    if (lane < 52) h_s[lane] = 0.f;
    float c = 0.f;
    LW();

    const size_t base = (size_t)b * 512;
    const int c0 = dir * 200 + u;

    float xv0 = 0.f, xv1 = 0.f, xv2 = 0.f, xv3 = 0.f;
    {
        const int t0 = dir ? 511 : 0;
        if (act) {
            const float* xr = xw + (base + t0) * 400 + c0;
            xv0 = xr[0]; xv1 = xr[50]; xv2 = xr[100]; xv3 = xr[150];
        }
    }

    for (int it = 0; it < 512; ++it) {
        const int t = dir ? (511 - it) : it;
        const float xc0 = xv0, xc1 = xv1, xc2 = xv2, xc3 = xv3;
        if (it + 1 < 512) {
            const int tn = dir ? (510 - it) : (it + 1);
            if (act) {
                const float* xr = xw + (base + tn) * 400 + c0;
                xv0 = xr[0]; xv1 = xr[50]; xv2 = xr[100]; xv3 = xr[150];
            }
        }

        // broadcast-read h into registers (uniform addresses)
        float hv[52];
        {
            const f32x4* h4 = (const f32x4*)h_s;
            #pragma unroll
            for (int q = 0; q < 13; ++q) {
                const f32x4 v = h4[q];
                hv[4 * q + 0] = v[0]; hv[4 * q + 1] = v[1];
                hv[4 * q + 2] = v[2]; hv[4 * q + 3] = v[3];
            }
        }

        // four gate-sum chains, j ascending (identical order to R1)
        float s0 = bg0 + xc0, s1 = bg1 + xc1, s2 = bg2 + xc2, s3 = bg3 + xc3;
        #define FMA0(g, j) { float r_; \
            asm volatile("v_accvgpr_read_b32 %0, %1" : "=v"(r_) : "a"(W0##_##j)); \
            s0 = fmaf(r_, hv[j], s0); }
        #define FMAg(g, j, S) { float r_; \
            asm volatile("v_accvgpr_read_b32 %0, %1" : "=v"(r_) : "a"(W##g##_##j)); \
            S = fmaf(r_, hv[j], S); }
        #define F0(g, j) FMAg(0, j, s0)
        #define F1(g, j) FMAg(1, j, s1)
        #define F2(g, j) FMAg(2, j, s2)
        #define F3(g, j) FMAg(3, j, s3)
        REP50(F0, 0);
        REP50(F1, 1);
        REP50(F2, 2);
        REP50(F3, 3);
        #undef FMA0
        #undef FMAg
        #undef F0
        #undef F1
        #undef F2
        #undef F3

        if (act) {
            const float gi = s0;
            const float gf = s1;
            const float gg = s2;
            const float go = s3;
            const float si = 1.f / (1.f + expf(-gi));
            const float sf = 1.f / (1.f + expf(-gf));
            const float so = 1.f / (1.f + expf(-go));
            c = sf * c + si * tanhf(gg);
            const float h = so * tanhf(c);
            hout[(base + t) * 100 + dir * 50 + u] = h;
            h_s[u] = h;
        }
        LW();   // single-wave: order h_s write before next iteration's reads
    }
}

// ---------------------------------------------------------------------------
// Kernel 3: emissions logits[bt][11] = hout[bt][100] @ Wout^T + bout
// ---------------------------------------------------------------------------
__global__ __launch_bounds__(256) void k_emis(
    const float* __restrict__ hout,   // [131072][100]
    const float* __restrict__ Wout,   // [11][100]
    const float* __restrict__ bout,   // [11]
    float* __restrict__ logits)       // [131072][11]
{
    __shared__ float Wl[1104];
    __shared__ float bl[11];
    const int tid = threadIdx.x;
    for (int i = tid; i < 1100; i += 256) Wl[i] = Wout[i];
    if (tid < 11) bl[tid] = bout[tid];
    __syncthreads();

    const size_t bt = (size_t)blockIdx.x * 256 + tid;
    const float4* h4 = (const float4*)(hout + bt * 100);
    float acc[11];
    #pragma unroll
    for (int k = 0; k < 11; ++k) acc[k] = bl[k];
    #pragma unroll
    for (int q = 0; q < 25; ++q) {
        float4 v = h4[q];
        #pragma unroll
        for (int k = 0; k < 11; ++k) {
            const float4 wv = *(const float4*)&Wl[k * 100 + q * 4];
            acc[k] = fmaf(v.x, wv.x, fmaf(v.y, wv.y, fmaf(v.z, wv.z, fmaf(v.w, wv.w, acc[k]))));
        }
    }
    #pragma unroll
    for (int k = 0; k < 11; ++k) logits[bt * 11 + k] = acc[k];
}

// ---------------------------------------------------------------------------
// Kernel 4: CRF forward scan + logsumexp score + fused Viterbi backtrace.
// Register-resident scan (R11, absmax 0.0).
// ---------------------------------------------------------------------------
__global__ __launch_bounds__(64, 1) void k_crf(
    const float* __restrict__ logits,   // [131072][11]
    const int* __restrict__ mask,       // [256][512]
    const float* __restrict__ trans,    // [11][11]
    float* __restrict__ scores,         // [256]
    float* __restrict__ paths)          // [256][512] (as float)
{
    const int b = blockIdx.x;
    const int lane = threadIdx.x;
    const int lanec = (lane < 11) ? lane : 10;   // clamp for safe addressing

    __shared__ unsigned char bp[512][12];

    float trc[11], E[11];
    #pragma unroll
    for (int p = 0; p < 11; ++p) {
        trc[p] = trans[p * 11 + lanec];
        E[p]   = expf(trc[p]);                   // once; amortized over 512 steps
    }

    float al_c = (lane == 9) ? 0.f : -1000.f;    // alpha[c] lives in lane c (<11)

    const size_t lbase = (size_t)b * 512;

    float f_cur = logits[lbase * 11 + lanec];
    int   m_cur = mask[lbase];

    for (int t = 0; t < 512; ++t) {
        float f_next = 0.f; int m_next = 1;
        if (t + 1 < 512) {
            f_next = logits[(lbase + t + 1) * 11 + lanec];
            m_next = mask[lbase + t + 1];
        }

        float a[11];
        #pragma unroll
        for (int p = 0; p < 11; ++p) a[p] = __shfl(al_c, p);

        float vmax = a[0] + trc[0]; int amax = 0;
        #pragma unroll
        for (int p = 1; p < 11; ++p) {
            const float vp = a[p] + trc[p];
            if (vp > vmax) { vmax = vp; amax = p; }
        }

        const float m01 = fmaxf(a[0], a[1]),  m23 = fmaxf(a[2], a[3]);
        const float m45 = fmaxf(a[4], a[5]),  m67 = fmaxf(a[6], a[7]);
        const float m89 = fmaxf(a[8], a[9]);
        const float mA  = fmaxf(fmaxf(m01, m23), fmaxf(m45, m67));
        const float M   = fmaxf(mA, fmaxf(m89, a[10]));

        float e[11];
        #pragma unroll
        for (int p = 0; p < 11; ++p) e[p] = __expf(a[p] - M) * E[p];
        const float s01 = e[0] + e[1], s23 = e[2] + e[3];
        const float s45 = e[4] + e[5], s67 = e[6] + e[7];
        const float s89 = e[8] + e[9];
        const float S = ((s01 + s23) + (s45 + s67)) + (s89 + e[10]);

        const float na = f_cur + (M + __logf(S));

        if (lane < 11) {
            if (m_cur > 0) {
                al_c = na;
                bp[t][lane] = (unsigned char)amax;
            } else {
                bp[t][lane] = (unsigned char)lane;
            }
        }
        f_cur = f_next;
        m_cur = m_next;
    }

    float fin = (lane < 11) ? (al_c + trans[lane * 11 + 10]) : -1e30f;
    float m = fin;
    int am = (lane < 11) ? lane : 1000;
    #pragma unroll
    for (int off = 8; off >= 1; off >>= 1) {
        float om = __shfl_xor(m, off, 16);
        int   oa = __shfl_xor(am, off, 16);
        if (om > m || (om == m && oa < am)) { m = om; am = oa; }
    }
    float s = (lane < 11) ? expf(fin - m) : 0.f;
    #pragma unroll
    for (int off = 8; off >= 1; off >>= 1) s += __shfl_xor(s, off, 16);

    if (lane == 0) {
        scores[b] = m + logf(s);
        int cur = am;
        paths[lbase + 511] = (float)cur;
        for (int t = 511; t >= 1; --t) {
            cur = bp[t][cur];
            paths[lbase + t - 1] = (float)cur;
        }
    }
}

// ---------------------------------------------------------------------------
extern "C" void kernel_launch(void* const* d_in, const int* in_sizes, int n_in,
                              void* d_out, int out_size, void* d_ws, size_t ws_size,
                              hipStream_t stream) {
    const float* emb   = (const float*)d_in[0];
    const int*   imask = (const int*)d_in[1];
    const float* Wihf  = (const float*)d_in[2];
    const float* Whhf  = (const float*)d_in[3];
    const float* bf_   = (const float*)d_in[4];
    const float* Wihb  = (const float*)d_in[5];
    const float* Whhb  = (const float*)d_in[6];
    const float* bb_   = (const float*)d_in[7];
    const float* Wout  = (const float*)d_in[8];
    const float* bout  = (const float*)d_in[9];
    const float* trans = (const float*)d_in[10];

    float* out = (float*)d_out;
    float* ws  = (float*)d_ws;
    float* xw     = ws;                          // 131072*400 f32 = 209.7 MB
    float* hout   = xw + (size_t)131072 * 400;   // 131072*100 f32 = 52.4 MB
    float* logits = hout + (size_t)131072 * 100; // 131072*11  f32 = 5.8 MB

    // Bh/Bl (614 KB each) live in the hout region: consumed by k_gemm_split,
    // overwritten afterwards by k_lstm. Zero extra workspace.
    _Float16* Bh = (_Float16*)hout;
    _Float16* Bl = Bh + (size_t)400 * 768;

    k_bsplit<<<1200, 256, 0, stream>>>(Wihf, Wihb, Bh, Bl);
    k_gemm_split<<<5120, 256, 0, stream>>>(emb, Bh, Bl, xw);
    k_lstm<<<1024, 64, 0, stream>>>(xw, Whhf, Whhb, bf_, bb_, hout);
    k_emis<<<512, 256, 0, stream>>>(hout, Wout, bout, logits);
    k_crf<<<256, 64, 0, stream>>>(logits, imask, trans, out, out + 256);
}

// Round 16
// 975.765 us; speedup vs baseline: 1.2910x; 1.2910x over previous
//
#include <hip/hip_runtime.h>
#include <math.h>

// Problem constants
// B=256, T=512, E=768, Hd=50, 4*Hd=200, H=100, K=11, START=9, STOP=10, NEG=-1000
// M = B*T = 131072

typedef _Float16 half8 __attribute__((ext_vector_type(8)));
typedef _Float16 half4 __attribute__((ext_vector_type(4)));
typedef float f32x4 __attribute__((ext_vector_type(4)));

// Non-draining workgroup barrier (learn_hip m201 pattern): LDS visibility
// only — no vmcnt drain, so prefetch loads issued before the barrier stay
// in flight across it. sched_barrier(0) pins ds ops on both sides.
#define LBAR() do {                                   \
    __builtin_amdgcn_sched_barrier(0);                \
    asm volatile("s_waitcnt lgkmcnt(0)");             \
    __builtin_amdgcn_s_barrier();                     \
    __builtin_amdgcn_sched_barrier(0);                \
} while (0)

// ---------------------------------------------------------------------------
// Kernel 0: one-time hi/lo fp16 split of concat(W_ih_f, W_ih_b) [400][768].
// ---------------------------------------------------------------------------
__global__ __launch_bounds__(256) void k_bsplit(
    const float* __restrict__ Wf,     // [200][768]
    const float* __restrict__ Wb,     // [200][768]
    _Float16* __restrict__ Bh,        // [400*768]
    _Float16* __restrict__ Bl)
{
    const int i = blockIdx.x * 256 + threadIdx.x;   // 0..307199
    if (i < 400 * 768) {
        const int n = i / 768;
        const int k = i - n * 768;
        const float v = (n < 200) ? Wf[n * 768 + k] : Wb[(n - 200) * 768 + k];
        const _Float16 hi = (_Float16)v;
        Bh[i] = hi;
        Bl[i] = (_Float16)(v - (float)hi);
    }
}

// ---------------------------------------------------------------------------
// Kernel 1: xw[M][400] = emb[M][768] @ concat(W_ih_f, W_ih_b)^T
// Split-precision fp16 MFMA; non-draining LBAR K-loop; pre-split B.
// (R13 configuration — best measured, ~320 us, 772 TF effective = ~86% of
// the m97-structure ceiling for this tile shape.)
// ---------------------------------------------------------------------------
__global__ __launch_bounds__(256) void k_gemm_split(
    const float* __restrict__ emb,
    const _Float16* __restrict__ Bhg, // [400][768] pre-split hi
    const _Float16* __restrict__ Blg, // [400][768] pre-split lo
    float* __restrict__ xw)           // [M][400]
{
    __shared__ _Float16 Ah[128 * 64];
    __shared__ _Float16 Al[128 * 64];
    __shared__ _Float16 Bh[80 * 64];
    __shared__ _Float16 Bl[80 * 64];

    const int bid = blockIdx.x;
    const int wg  = (bid & 7) * 640 + (bid >> 3);
    const int mt  = wg / 5;
    const int nb  = wg - mt * 5;
    const size_t m0 = (size_t)mt * 128;
    const int n0 = nb * 80;

    const int tid  = threadIdx.x;
    const int lane = tid & 63;
    const int w    = tid >> 6;        // wave 0..3, rows w*32..+31
    const int grp  = lane >> 4;       // 0..3
    const int r16  = lane & 15;

    f32x4 acc[2][5];
    #pragma unroll
    for (int m = 0; m < 2; ++m)
        #pragma unroll
        for (int n = 0; n < 5; ++n) acc[m][n] = (f32x4){0.f, 0.f, 0.f, 0.f};

    // prefetch kt=0
    float4 apf[8];
    half4  bph[5], bpl[5];
    #pragma unroll
    for (int j = 0; j < 8; ++j) {
        const int flat = j * 256 + tid;
        const int row  = flat >> 4;
        const int q    = flat & 15;
        apf[j] = *(const float4*)(emb + (m0 + row) * 768 + q * 4);
    }
    #pragma unroll
    for (int j = 0; j < 5; ++j) {
        const int flat = j * 256 + tid;      // 0..1279
        const int row  = flat >> 4;          // 0..79
        const int q    = flat & 15;
        const size_t src = (size_t)(n0 + row) * 768 + q * 4;
        bph[j] = *(const half4*)(Bhg + src);
        bpl[j] = *(const half4*)(Blg + src);
    }

    for (int kt = 0; kt < 12; ++kt) {
        LBAR();   // all waves done reading LDS from previous iteration

        #pragma unroll
        for (int j = 0; j < 8; ++j) {
            const int flat = j * 256 + tid;
            const int row  = flat >> 4;
            const int q    = flat & 15;
            const float4 v = apf[j];
            half4 hv, lv;
            hv[0] = (_Float16)v.x; lv[0] = (_Float16)(v.x - (float)hv[0]);
            hv[1] = (_Float16)v.y; lv[1] = (_Float16)(v.y - (float)hv[1]);
            hv[2] = (_Float16)v.z; lv[2] = (_Float16)(v.z - (float)hv[2]);
            hv[3] = (_Float16)v.w; lv[3] = (_Float16)(v.w - (float)hv[3]);
            const int s    = (q >> 1) ^ (row & 7);
            const int addr = row * 64 + s * 8 + (q & 1) * 4;
            *(half4*)(Ah + addr) = hv;
            *(half4*)(Al + addr) = lv;
        }
        #pragma unroll
        for (int j = 0; j < 5; ++j) {
            const int flat = j * 256 + tid;
            const int row  = flat >> 4;
            const int q    = flat & 15;
            const int s    = (q >> 1) ^ (row & 7);
            const int addr = row * 64 + s * 8 + (q & 1) * 4;
            *(half4*)(Bh + addr) = bph[j];
            *(half4*)(Bl + addr) = bpl[j];
        }

        if (kt + 1 < 12) {
            const int k0 = (kt + 1) * 64;
            #pragma unroll
            for (int j = 0; j < 8; ++j) {
                const int flat = j * 256 + tid;
                const int row  = flat >> 4;
                const int q    = flat & 15;
                apf[j] = *(const float4*)(emb + (m0 + row) * 768 + k0 + q * 4);
            }
            #pragma unroll
            for (int j = 0; j < 5; ++j) {
                const int flat = j * 256 + tid;
                const int row  = flat >> 4;
                const int q    = flat & 15;
                const size_t src = (size_t)(n0 + row) * 768 + k0 + q * 4;
                bph[j] = *(const half4*)(Bhg + src);
                bpl[j] = *(const half4*)(Blg + src);
            }
        }

        LBAR();   // staged tile visible; prefetch stays in flight

        #pragma unroll
        for (int ks = 0; ks < 2; ++ks) {
            const int kslot = ks * 4 + grp;
            half8 ah[2], al[2], bh[5], bl[5];
            #pragma unroll
            for (int m = 0; m < 2; ++m) {
                const int row = w * 32 + m * 16 + r16;
                const int ad  = row * 64 + (kslot ^ (row & 7)) * 8;
                ah[m] = *(half8*)(Ah + ad);
                al[m] = *(half8*)(Al + ad);
            }
            #pragma unroll
            for (int n = 0; n < 5; ++n) {
                const int row = n * 16 + r16;
                const int ad  = row * 64 + (kslot ^ (row & 7)) * 8;
                bh[n] = *(half8*)(Bh + ad);
                bl[n] = *(half8*)(Bl + ad);
            }
            #pragma unroll
            for (int m = 0; m < 2; ++m)
                #pragma unroll
                for (int n = 0; n < 5; ++n) {
                    acc[m][n] = __builtin_amdgcn_mfma_f32_16x16x32_f16(ah[m], bh[n], acc[m][n], 0, 0, 0);
                    acc[m][n] = __builtin_amdgcn_mfma_f32_16x16x32_f16(ah[m], bl[n], acc[m][n], 0, 0, 0);
                    acc[m][n] = __builtin_amdgcn_mfma_f32_16x16x32_f16(al[m], bh[n], acc[m][n], 0, 0, 0);
                }
        }
    }

    #pragma unroll
    for (int m = 0; m < 2; ++m) {
        #pragma unroll
        for (int n = 0; n < 5; ++n) {
            #pragma unroll
            for (int i = 0; i < 4; ++i) {
                const size_t row = m0 + w * 32 + m * 16 + (lane >> 4) * 4 + i;
                const int    col = n0 + n * 16 + (lane & 15);
                xw[row * 400 + col] = acc[m][n][i];
            }
        }
    }
}

// ---------------------------------------------------------------------------
// Kernel 2: bidirectional LSTM recurrence. One block per (batch, dir).
// R1 structure verbatim — the established floor (457 us) after 10 failed
// structural variants spanning every axis: barriers (2/1/0, draining/not),
// weight home (L2-stream / LDS-WT4 / AGPR-parked), transcendentals
// (libm/fast), prefetch depth (1/4/8), chains-per-block (1/2/16), and
// waves-per-block (4/1, LDS-exchange/shfl/zero-exchange). Per-step time
// (~2100 cy) is the serial recurrence chain itself at 2 chains/CU; only
// more independent chains per CU could beat it, and B=512 chains on 256
// CUs caps that at 2. DO NOT TOUCH.
// ---------------------------------------------------------------------------
__global__ __launch_bounds__(256) void k_lstm(
    const float* __restrict__ xw,     // [131072][400] (fwd gates 0..199, bwd 200..399)
    const float* __restrict__ Whh_f,  // [200][50]
    const float* __restrict__ Whh_b,
    const float* __restrict__ bf_,    // [200]
    const float* __restrict__ bb_,
    float* __restrict__ hout)         // [131072][100] (fwd 0..49, bwd 50..99)
{
    const int b   = blockIdx.x >> 1;
    const int dir = blockIdx.x & 1;
    const int g   = threadIdx.x;

    __shared__ float h_s[52];
    __shared__ float g_s[200];

    const float* Whh  = dir ? Whh_b : Whh_f;
    const float* bias = dir ? bb_ : bf_;

    float w[52];
    float bg = 0.f;
    if (g < 200) {
        #pragma unroll
        for (int j = 0; j < 50; ++j) w[j] = Whh[g * 50 + j];
        w[50] = 0.f; w[51] = 0.f;
        bg = bias[g];
    } else {
        #pragma unroll
        for (int j = 0; j < 52; ++j) w[j] = 0.f;
    }

    if (g < 52) h_s[g] = 0.f;
    float c = 0.f;
    __syncthreads();

    const size_t base = (size_t)b * 512;

    float xv = 0.f;
    {
        int t0 = dir ? 511 : 0;
        if (g < 200) xv = xw[(base + t0) * 400 + dir * 200 + g];
    }

    for (int it = 0; it < 512; ++it) {
        const int t = dir ? (511 - it) : it;
        float xcur = xv;
        if (it + 1 < 512) {
            int tn = dir ? (510 - it) : (it + 1);
            if (g < 200) xv = xw[(base + tn) * 400 + dir * 200 + g];
        }

        float sum = bg + xcur;
        const float4* h4 = (const float4*)h_s;
        #pragma unroll
        for (int q = 0; q < 13; ++q) {
            float4 hv = h4[q];
            sum = fmaf(w[q * 4 + 0], hv.x, sum);
            sum = fmaf(w[q * 4 + 1], hv.y, sum);
            sum = fmaf(w[q * 4 + 2], hv.z, sum);
            sum = fmaf(w[q * 4 + 3], hv.w, sum);
        }
        if (g < 200) g_s[g] = sum;
        __syncthreads();

        if (g < 50) {
            float gi = g_s[g];
            float gf = g_s[g + 50];
            float gg = g_s[g + 100];
            float go = g_s[g + 150];
            float si = 1.f / (1.f + expf(-gi));
            float sf = 1.f / (1.f + expf(-gf));
            float so = 1.f / (1.f + expf(-go));
            c = sf * c + si * tanhf(gg);
            float h = so * tanhf(c);
            hout[(base + t) * 100 + dir * 50 + g] = h;
            h_s[g] = h;
        }
        __syncthreads();
    }
}

// ---------------------------------------------------------------------------
// Kernel 3: emissions logits[bt][11] = hout[bt][100] @ Wout^T + bout
// ---------------------------------------------------------------------------
__global__ __launch_bounds__(256) void k_emis(
    const float* __restrict__ hout,   // [131072][100]
    const float* __restrict__ Wout,   // [11][100]
    const float* __restrict__ bout,   // [11]
    float* __restrict__ logits)       // [131072][11]
{
    __shared__ float Wl[1104];
    __shared__ float bl[11];
    const int tid = threadIdx.x;
    for (int i = tid; i < 1100; i += 256) Wl[i] = Wout[i];
    if (tid < 11) bl[tid] = bout[tid];
    __syncthreads();

    const size_t bt = (size_t)blockIdx.x * 256 + tid;
    const float4* h4 = (const float4*)(hout + bt * 100);
    float acc[11];
    #pragma unroll
    for (int k = 0; k < 11; ++k) acc[k] = bl[k];
    #pragma unroll
    for (int q = 0; q < 25; ++q) {
        float4 v = h4[q];
        #pragma unroll
        for (int k = 0; k < 11; ++k) {
            const float4 wv = *(const float4*)&Wl[k * 100 + q * 4];
            acc[k] = fmaf(v.x, wv.x, fmaf(v.y, wv.y, fmaf(v.z, wv.z, fmaf(v.w, wv.w, acc[k]))));
        }
    }
    #pragma unroll
    for (int k = 0; k < 11; ++k) logits[bt * 11 + k] = acc[k];
}

// ---------------------------------------------------------------------------
// Kernel 4: CRF forward scan + logsumexp score + fused Viterbi backtrace.
// Register-resident scan (R11, absmax 0.0): na = f[c] + M +
// log(sum_p exp(al[p]-M)*E[c][p]) with E precomputed; argmax first-max
// ascending over al[p]+trc[p] (f[c] cancels). Zero LDS in the scan loop.
// ---------------------------------------------------------------------------
__global__ __launch_bounds__(64, 1) void k_crf(
    const float* __restrict__ logits,   // [131072][11]
    const int* __restrict__ mask,       // [256][512]
    const float* __restrict__ trans,    // [11][11]
    float* __restrict__ scores,         // [256]
    float* __restrict__ paths)          // [256][512] (as float)
{
    const int b = blockIdx.x;
    const int lane = threadIdx.x;
    const int lanec = (lane < 11) ? lane : 10;   // clamp for safe addressing

    __shared__ unsigned char bp[512][12];

    float trc[11], E[11];
    #pragma unroll
    for (int p = 0; p < 11; ++p) {
        trc[p] = trans[p * 11 + lanec];
        E[p]   = expf(trc[p]);                   // once; amortized over 512 steps
    }

    float al_c = (lane == 9) ? 0.f : -1000.f;    // alpha[c] lives in lane c (<11)

    const size_t lbase = (size_t)b * 512;

    float f_cur = logits[lbase * 11 + lanec];
    int   m_cur = mask[lbase];

    for (int t = 0; t < 512; ++t) {
        float f_next = 0.f; int m_next = 1;
        if (t + 1 < 512) {
            f_next = logits[(lbase + t + 1) * 11 + lanec];
            m_next = mask[lbase + t + 1];
        }

        float a[11];
        #pragma unroll
        for (int p = 0; p < 11; ++p) a[p] = __shfl(al_c, p);

        float vmax = a[0] + trc[0]; int amax = 0;
        #pragma unroll
        for (int p = 1; p < 11; ++p) {
            const float vp = a[p] + trc[p];
            if (vp > vmax) { vmax = vp; amax = p; }
        }

        const float m01 = fmaxf(a[0], a[1]),  m23 = fmaxf(a[2], a[3]);
        const float m45 = fmaxf(a[4], a[5]),  m67 = fmaxf(a[6], a[7]);
        const float m89 = fmaxf(a[8], a[9]);
        const float mA  = fmaxf(fmaxf(m01, m23), fmaxf(m45, m67));
        const float M   = fmaxf(mA, fmaxf(m89, a[10]));

        float e[11];
        #pragma unroll
        for (int p = 0; p < 11; ++p) e[p] = __expf(a[p] - M) * E[p];
        const float s01 = e[0] + e[1], s23 = e[2] + e[3];
        const float s45 = e[4] + e[5], s67 = e[6] + e[7];
        const float s89 = e[8] + e[9];
        const float S = ((s01 + s23) + (s45 + s67)) + (s89 + e[10]);

        const float na = f_cur + (M + __logf(S));

        if (lane < 11) {
            if (m_cur > 0) {
                al_c = na;
                bp[t][lane] = (unsigned char)amax;
            } else {
                bp[t][lane] = (unsigned char)lane;
            }
        }
        f_cur = f_next;
        m_cur = m_next;
    }

    float fin = (lane < 11) ? (al_c + trans[lane * 11 + 10]) : -1e30f;
    float m = fin;
    int am = (lane < 11) ? lane : 1000;
    #pragma unroll
    for (int off = 8; off >= 1; off >>= 1) {
        float om = __shfl_xor(m, off, 16);
        int   oa = __shfl_xor(am, off, 16);
        if (om > m || (om == m && oa < am)) { m = om; am = oa; }
    }
    float s = (lane < 11) ? expf(fin - m) : 0.f;
    #pragma unroll
    for (int off = 8; off >= 1; off >>= 1) s += __shfl_xor(s, off, 16);

    if (lane == 0) {
        scores[b] = m + logf(s);
        int cur = am;
        paths[lbase + 511] = (float)cur;
        for (int t = 511; t >= 1; --t) {
            cur = bp[t][cur];
            paths[lbase + t - 1] = (float)cur;
        }
    }
}

// ---------------------------------------------------------------------------
extern "C" void kernel_launch(void* const* d_in, const int* in_sizes, int n_in,
                              void* d_out, int out_size, void* d_ws, size_t ws_size,
                              hipStream_t stream) {
    const float* emb   = (const float*)d_in[0];
    const int*   imask = (const int*)d_in[1];
    const float* Wihf  = (const float*)d_in[2];
    const float* Whhf  = (const float*)d_in[3];
    const float* bf_   = (const float*)d_in[4];
    const float* Wihb  = (const float*)d_in[5];
    const float* Whhb  = (const float*)d_in[6];
    const float* bb_   = (const float*)d_in[7];
    const float* Wout  = (const float*)d_in[8];
    const float* bout  = (const float*)d_in[9];
    const float* trans = (const float*)d_in[10];

    float* out = (float*)d_out;
    float* ws  = (float*)d_ws;
    float* xw     = ws;                          // 131072*400 f32 = 209.7 MB
    float* hout   = xw + (size_t)131072 * 400;   // 131072*100 f32 = 52.4 MB
    float* logits = hout + (size_t)131072 * 100; // 131072*11  f32 = 5.8 MB

    // Bh/Bl (614 KB each) live in the hout region: consumed by k_gemm_split,
    // overwritten afterwards by k_lstm. Zero extra workspace.
    _Float16* Bh = (_Float16*)hout;
    _Float16* Bl = Bh + (size_t)400 * 768;

    k_bsplit<<<1200, 256, 0, stream>>>(Wihf, Wihb, Bh, Bl);
    k_gemm_split<<<5120, 256, 0, stream>>>(emb, Bh, Bl, xw);
    k_lstm<<<512, 256, 0, stream>>>(xw, Whhf, Whhb, bf_, bb_, hout);
    k_emis<<<512, 256, 0, stream>>>(hout, Wout, bout, logits);
    k_crf<<<256, 64, 0, stream>>>(logits, imask, trans, out, out + 256);
}